// Round 13
// baseline (45.495 us; speedup 1.0000x reference)
//
#include <hip/hip_runtime.h>
#include <hip/hip_bf16.h>

#define OUT_N 8192
#define IN_K  8192
#define M_ROWS 64

typedef __attribute__((ext_vector_type(8))) short  bf16x8;
typedef __attribute__((ext_vector_type(4))) float  f32x4;
typedef __attribute__((ext_vector_type(4))) int    int4v;
typedef __attribute__((ext_vector_type(2))) int    int2v;

__device__ const float NF4_TAB[16] = {
  -1.0f, -0.6961928009986877f, -0.5250730514526367f, -0.39491748809814453f,
  -0.28444138169288635f, -0.18477343022823334f, -0.09105003625154495f, 0.0f,
  0.07958029955625534f, 0.16093020141124725f, 0.24611230850219726f,
  0.33791524171829224f, 0.44070982933044434f, 0.5626170039176941f,
  0.7229568362236023f, 1.0f };

static __device__ __forceinline__ unsigned short f2bf(float f) {
  union { __hip_bfloat16 h; unsigned short s; } u;
  u.h = __float2bfloat16(f);
  return u.s;
}

// Repack x (fp32 [64][8192]) -> bf16 MFMA A-fragment order.
// xf[((ks*4 + mt)*64 + lane)*8 + j] = bf16(x[mt*16+(lane&15)][ks*32+(lane>>4)*8+j])
__global__ __launch_bounds__(256) void qlin_prep(const float* __restrict__ x,
                                                 unsigned short* __restrict__ xf) {
  int t = blockIdx.x * 256 + threadIdx.x;          // (ks, mt, lane)
  int lane = t & 63, mt = (t >> 6) & 3, ks = t >> 8;
  int ri = lane & 15, kbb = lane >> 4;
  const float* src = x + (size_t)(mt * 16 + ri) * IN_K + ks * 32 + kbb * 8;
  f32x4 a = *(const f32x4*)src;
  f32x4 c = *(const f32x4*)(src + 4);
  bf16x8 o;
  o[0] = (short)f2bf(a[0]); o[1] = (short)f2bf(a[1]);
  o[2] = (short)f2bf(a[2]); o[3] = (short)f2bf(a[3]);
  o[4] = (short)f2bf(c[0]); o[5] = (short)f2bf(c[1]);
  o[6] = (short)f2bf(c[2]); o[7] = (short)f2bf(c[3]);
  ((bf16x8*)xf)[t] = o;
}

// dequant 4 packed code-bytes + scale by amax (lane-uniform over B-fragment):
// 4 pair-LUT reads -> unpack to f32 -> *am -> repack bf16 (cvt_pk by compiler)
static __device__ __forceinline__ bf16x8 deqscale(const unsigned int* lut,
                                                  unsigned b, float am) {
  unsigned p0 = lut[b & 255];
  unsigned p1 = lut[(b >> 8) & 255];
  unsigned p2 = lut[(b >> 16) & 255];
  unsigned p3 = lut[b >> 24];
  bf16x8 r;
  r[0] = (short)f2bf(__uint_as_float(p0 << 16) * am);
  r[1] = (short)f2bf(__uint_as_float(p0 & 0xffff0000u) * am);
  r[2] = (short)f2bf(__uint_as_float(p1 << 16) * am);
  r[3] = (short)f2bf(__uint_as_float(p1 & 0xffff0000u) * am);
  r[4] = (short)f2bf(__uint_as_float(p2 << 16) * am);
  r[5] = (short)f2bf(__uint_as_float(p2 & 0xffff0000u) * am);
  r[6] = (short)f2bf(__uint_as_float(p3 << 16) * am);
  r[7] = (short)f2bf(__uint_as_float(p3 & 0xffff0000u) * am);
  return r;
}

// one k-step, barrier-free: issue A-prefetch (ks+1, L2-fast, OLDER than pk so
// A-waits never drain the HBM pk stream) and pk refill (ks+4), then
// bpermute-redistribute + dequant+scale + 4 MFMA accumulating into mn.
#define QSTEP(U4, PKV, AMV) {                                                 \
    int aks = KS + (U4) + 1; if (aks > NITm1) aks = NITm1;                    \
    int pks = KS + (U4) + 4; if (pks > NITm1) pks = NITm1;                    \
    const char* _ap = xbase + (size_t)aks * 4096;                             \
    bf16x8 n0 = *(const bf16x8*)(_ap);                                        \
    bf16x8 n1 = *(const bf16x8*)(_ap + 1024);                                 \
    bf16x8 n2 = *(const bf16x8*)(_ap + 2048);                                 \
    bf16x8 n3 = *(const bf16x8*)(_ap + 3072);                                 \
    int4v npk = *(const int4v*)(pcoal + (size_t)pks * 64);                    \
    unsigned _pkd = (unsigned)PKV[0] | ((unsigned)PKV[1] << 8)                \
                  | ((unsigned)PKV[2] << 16) | ((unsigned)PKV[3] << 24);      \
    unsigned _bp = (unsigned)__builtin_amdgcn_ds_bpermute(bpidx, (int)_pkd);  \
    bf16x8 b = deqscale(lut, _bp, AMV);                                       \
    mn0 = __builtin_amdgcn_mfma_f32_16x16x32_bf16(A0, b, mn0, 0, 0, 0);       \
    mn1 = __builtin_amdgcn_mfma_f32_16x16x32_bf16(A1, b, mn1, 0, 0, 0);       \
    mn2 = __builtin_amdgcn_mfma_f32_16x16x32_bf16(A2, b, mn2, 0, 0, 0);       \
    mn3 = __builtin_amdgcn_mfma_f32_16x16x32_bf16(A3, b, mn3, 0, 0, 0);       \
    A0 = n0; A1 = n1; A2 = n2; A3 = n3; PKV = npk; }

// Fused NF4 dequant + GEMM. BARRIER-FREE main loop (R6 skeleton): free-running
// waves, A-fragments direct from L2-resident xf (1-deep named prefetch),
// coalesced pk (16-sector) + single packed ds_bpermute, 4-deep named pk ring.
// absmax folded into the B-fragment in f32 before MFMA (lane-uniform).
template<int NC>
__global__ __launch_bounds__(256, 4) void qlin_main(
    const int*   __restrict__ packed,
    const float* __restrict__ absmax,
    const unsigned short* __restrict__ xf,
    unsigned short* __restrict__ parts) {
  constexpr int KCn   = IN_K / NC;     // k per chunk
  constexpr int NIT   = KCn / 32;      // k-steps per chunk (32 for NC=8)
  constexpr int NITm1 = NIT - 1;
  constexpr int NGRP  = NIT / 4;
  constexpr int AMX   = NIT / 2 - 1;   // last absmax group in chunk
  constexpr int LOG   = (NC == 8) ? 3 : 2;

  __shared__ unsigned int lut[256];    // byte -> {bf16(nf4[lo]), bf16(nf4[hi])}
  __shared__ float tl[64 * 68];        // epilogue transpose tile (17 KB)
  {
    int t = threadIdx.x;
    unsigned lo = f2bf(NF4_TAB[t & 15]);
    unsigned hi = f2bf(NF4_TAB[(t >> 4) & 15]);
    lut[t] = lo | (hi << 16);
  }
  __syncthreads();

  const int l     = threadIdx.x & 63;
  const int w     = threadIdx.x >> 6;
  const int ntile = (int)blockIdx.x >> LOG;
  const int chunk = (int)blockIdx.x & (NC - 1);   // ~XCD id -> xf L2 locality
  const int colg0 = ntile * 64 + w * 16;
  const int col   = colg0 + (l & 15);
  const int kb    = l >> 4;
  const int kc0   = chunk * KCn;
  const int ksg0  = kc0 >> 5;

  // coalesced pk: lane l reads 16B piece (l&3) of col colg0+(l>>2); kstep stride 64B
  const char* pcoal = (const char*)packed
                    + ((size_t)(colg0 + (l >> 2)) * (IN_K / 2) + kc0 / 2) * 4
                    + (l & 3) * 16;
  // dest lane (c=l&15, q=l>>4) pulls from src lane 4c+q (byte index for bpermute)
  const int bpidx = (((l & 15) << 2) | (l >> 4)) << 2;

  const char* xbase = (const char*)xf + (size_t)ksg0 * 4096 + l * 16;
  const float* aptr = absmax + (size_t)col * 128 + (kc0 >> 6);

  const f32x4 zro = {0.f, 0.f, 0.f, 0.f};
  f32x4 mn0 = zro, mn1 = zro, mn2 = zro, mn3 = zro;
  bf16x8 A0, A1, A2, A3;
  int4v pk0, pk1, pk2, pk3;

  // prologue: A(ks0), pk ring 0..3, first absmax pair
  A0 = *(const bf16x8*)(xbase);
  A1 = *(const bf16x8*)(xbase + 1024);
  A2 = *(const bf16x8*)(xbase + 2048);
  A3 = *(const bf16x8*)(xbase + 3072);
  pk0 = *(const int4v*)(pcoal);
  pk1 = *(const int4v*)(pcoal + 64);
  pk2 = *(const int4v*)(pcoal + 128);
  pk3 = *(const int4v*)(pcoal + 192);
  float amE = aptr[0], amO = aptr[1];

  for (int g = 0; g < NGRP; ++g) {
    const int KS = g * 4;
    int ia = 2 * g + 2; if (ia > AMX) ia = AMX;
    int ib = 2 * g + 3; if (ib > AMX) ib = AMX;
    float pmE = aptr[ia], pmO = aptr[ib];

    QSTEP(0, pk0, amE)
    QSTEP(1, pk1, amE)
    QSTEP(2, pk2, amO)
    QSTEP(3, pk3, amO)

    amE = pmE; amO = pmO;
  }

  // epilogue: transpose 64x64 fp32 tile through LDS (stride 68 dwords), then
  // bf16-pack + fully-contiguous tile-major stores.
  {
    const int c  = w * 16 + (l & 15);        // block-local col
    const int r0 = kb * 4;
    tl[(0  + r0 + 0) * 68 + c] = mn0[0];
    tl[(0  + r0 + 1) * 68 + c] = mn0[1];
    tl[(0  + r0 + 2) * 68 + c] = mn0[2];
    tl[(0  + r0 + 3) * 68 + c] = mn0[3];
    tl[(16 + r0 + 0) * 68 + c] = mn1[0];
    tl[(16 + r0 + 1) * 68 + c] = mn1[1];
    tl[(16 + r0 + 2) * 68 + c] = mn1[2];
    tl[(16 + r0 + 3) * 68 + c] = mn1[3];
    tl[(32 + r0 + 0) * 68 + c] = mn2[0];
    tl[(32 + r0 + 1) * 68 + c] = mn2[1];
    tl[(32 + r0 + 2) * 68 + c] = mn2[2];
    tl[(32 + r0 + 3) * 68 + c] = mn2[3];
    tl[(48 + r0 + 0) * 68 + c] = mn3[0];
    tl[(48 + r0 + 1) * 68 + c] = mn3[1];
    tl[(48 + r0 + 2) * 68 + c] = mn3[2];
    tl[(48 + r0 + 3) * 68 + c] = mn3[3];
    __syncthreads();
    // parts layout: [chunk][tile][row 64][col 64] bf16 -> block tile contiguous
    unsigned short* po = parts + ((size_t)chunk * 128 + ntile) * 4096;
    const int t  = threadIdx.x;
    const int rr = t >> 4;          // row within pass (0..15)
    const int cq = (t & 15) * 4;    // col quad
    #pragma unroll
    for (int p = 0; p < 4; ++p) {
      const int row = p * 16 + rr;
      f32x4 v = *(const f32x4*)&tl[row * 68 + cq];
      int2v o;
      o[0] = (int)(f2bf(v[0]) | ((unsigned)f2bf(v[1]) << 16));
      o[1] = (int)(f2bf(v[2]) | ((unsigned)f2bf(v[3]) << 16));
      *(int2v*)(po + (size_t)row * 64 + cq) = o;
    }
  }
}

// reduce bf16 tile-major partials: out[row][tile*64+col] = sum_c parts + bias
template<int NC>
__global__ __launch_bounds__(256) void qlin_reduce(
    const unsigned short* __restrict__ parts,
    const float* __restrict__ bias,
    float*       __restrict__ out) {
  int e = blockIdx.x * 256 + threadIdx.x;          // octet index (8 cols)
  if (e >= M_ROWS * OUT_N / 8) return;
  const int tile = e >> 9;          // 512 octets per tile (64 rows x 8)
  const int rem  = e & 511;
  const int row  = rem >> 3;
  const int oct  = rem & 7;
  const size_t base = ((size_t)tile * 64 + row) * 64 + oct * 8;
  constexpr size_t CS = (size_t)128 * 64 * 64;     // chunk stride (elements)
  float s[8] = {0,0,0,0,0,0,0,0};
  #pragma unroll
  for (int c = 0; c < NC; ++c) {
    bf16x8 v = *(const bf16x8*)(parts + c * CS + base);
    #pragma unroll
    for (int j = 0; j < 8; ++j)
      s[j] += __uint_as_float(((unsigned)(unsigned short)v[j]) << 16);
  }
  const int colb = tile * 64 + oct * 8;
  const f32x4* bp = (const f32x4*)(bias + colb);
  f32x4 b0 = bp[0], b1 = bp[1];
  f32x4 o0, o1;
  o0[0] = s[0] + b0[0]; o0[1] = s[1] + b0[1];
  o0[2] = s[2] + b0[2]; o0[3] = s[3] + b0[3];
  o1[0] = s[4] + b1[0]; o1[1] = s[5] + b1[1];
  o1[2] = s[6] + b1[2]; o1[3] = s[7] + b1[3];
  float* op = out + (size_t)row * OUT_N + colb;
  *(f32x4*)op = o0;
  *(f32x4*)(op + 4) = o1;
}

extern "C" void kernel_launch(void* const* d_in, const int* in_sizes, int n_in,
                              void* d_out, int out_size, void* d_ws, size_t ws_size,
                              hipStream_t stream) {
  const float* x      = (const float*)d_in[0];
  const int*   packed = (const int*)d_in[1];
  const float* absmax = (const float*)d_in[2];
  const float* bias   = (const float*)d_in[3];
  float* out = (float*)d_out;

  unsigned short* xf    = (unsigned short*)d_ws;                      // 1 MB
  unsigned short* parts = (unsigned short*)((char*)d_ws + (1 << 20)); // NC MB bf16

  qlin_prep<<<(M_ROWS * IN_K / 8 + 255) / 256, 256, 0, stream>>>(x, xf);

  const size_t chunk_bytes = (size_t)128 * 64 * 64 * sizeof(unsigned short); // 1 MB
  const size_t need8 = (size_t)(1 << 20) + 8 * chunk_bytes;
  if (ws_size >= need8) {
    qlin_main<8><<<128 * 8, 256, 0, stream>>>(packed, absmax, xf, parts);
    qlin_reduce<8><<<(M_ROWS * OUT_N / 8 + 255) / 256, 256, 0, stream>>>(parts, bias, out);
  } else {
    qlin_main<4><<<128 * 4, 256, 0, stream>>>(packed, absmax, xf, parts);
    qlin_reduce<4><<<(M_ROWS * OUT_N / 8 + 255) / 256, 256, 0, stream>>>(parts, bias, out);
  }
}

// Round 14
// 42.802 us; speedup vs baseline: 1.0629x; 1.0629x over previous
//
#include <hip/hip_runtime.h>
#include <hip/hip_bf16.h>

#define OUT_N 8192
#define IN_K  8192
#define M_ROWS 64

typedef __attribute__((ext_vector_type(8))) short  bf16x8;
typedef __attribute__((ext_vector_type(4))) float  f32x4;
typedef __attribute__((ext_vector_type(4))) int    int4v;

__device__ const float NF4_TAB[16] = {
  -1.0f, -0.6961928009986877f, -0.5250730514526367f, -0.39491748809814453f,
  -0.28444138169288635f, -0.18477343022823334f, -0.09105003625154495f, 0.0f,
  0.07958029955625534f, 0.16093020141124725f, 0.24611230850219726f,
  0.33791524171829224f, 0.44070982933044434f, 0.5626170039176941f,
  0.7229568362236023f, 1.0f };

static __device__ __forceinline__ unsigned short f2bf(float f) {
  union { __hip_bfloat16 h; unsigned short s; } u;
  u.h = __float2bfloat16(f);
  return u.s;
}

static __device__ __forceinline__ void gload_lds16(const void* g, void* s) {
  __builtin_amdgcn_global_load_lds((const __attribute__((address_space(1))) void*)g,
                                   (__attribute__((address_space(3))) void*)s,
                                   16, 0, 0);
}

// Repack x (fp32 [64][8192]) -> bf16 MFMA A-fragment order.
// xf[((ks*4 + mt)*64 + lane)*8 + j] = bf16(x[mt*16+(lane&15)][ks*32+(lane>>4)*8+j])
__global__ __launch_bounds__(256) void qlin_prep(const float* __restrict__ x,
                                                 unsigned short* __restrict__ xf) {
  int t = blockIdx.x * 256 + threadIdx.x;          // (ks, mt, lane)
  int lane = t & 63, mt = (t >> 6) & 3, ks = t >> 8;
  int ri = lane & 15, kbb = lane >> 4;
  const float* src = x + (size_t)(mt * 16 + ri) * IN_K + ks * 32 + kbb * 8;
  f32x4 a = *(const f32x4*)src;
  f32x4 c = *(const f32x4*)(src + 4);
  bf16x8 o;
  o[0] = (short)f2bf(a[0]); o[1] = (short)f2bf(a[1]);
  o[2] = (short)f2bf(a[2]); o[3] = (short)f2bf(a[3]);
  o[4] = (short)f2bf(c[0]); o[5] = (short)f2bf(c[1]);
  o[6] = (short)f2bf(c[2]); o[7] = (short)f2bf(c[3]);
  ((bf16x8*)xf)[t] = o;
}

// dequant a packed-4-codes dword: 4 pair-LUT reads -> 8 ready bf16 weights
static __device__ __forceinline__ bf16x8 deq(const unsigned int* lut, unsigned b) {
  int4v bw;
  bw[0] = (int)lut[b & 255];
  bw[1] = (int)lut[(b >> 8) & 255];
  bw[2] = (int)lut[(b >> 16) & 255];
  bw[3] = (int)lut[b >> 24];
  union { int4v i; bf16x8 h; } c; c.i = bw;
  return c.h;
}

// Shared-memory overlay: main-loop state (lut + half-A staging) vs epilogue
// bf16 transpose tile. 17408 bytes total -> 9 blocks/CU by LDS.
union SMem {
  struct {
    unsigned int lut[256];        // byte -> {bf16(nf4[lo]), bf16(nf4[hi])}
    bf16x8 ast[2][4][128];        // [buf][kstep-in-phase][mt(0,1)*64+lane]
  } s;
  unsigned short tlb[64][72];     // epilogue transpose tile (stride 72 -> 16B rows)
};

// wave w stages k-step (4*PH + w), mt 0..1 only (rows 0-31), into buffer BUF.
#define STAGE(BUF, PH) {                                                      \
    const char* _s = xfb + (((size_t)(PH) * 4 + w) * 4096) + l * 16;          \
    gload_lds16(_s,        &ast[BUF][w][0]);                                  \
    gload_lds16(_s + 1024, &ast[BUF][w][64]); }

// one k-step: A2/A3 direct from L2 xf (issued OLDEST so their waits never
// drain the younger pk refill), A0/A1 typed ds_read, packed-byte bpermute,
// pair-LUT dequant, 4 MFMA. EVEN opens a 64k group (C=0), ODD closes (amax).
#define CSTEP_BODY(S, PKV)                                                    \
    int _pks = KS + (S) + 4; if (_pks > NITm1) _pks = NITm1;                  \
    const char* _gp = xfb + (size_t)(KS + (S)) * 4096 + l * 16;               \
    bf16x8 A2 = *(const bf16x8*)(_gp + 2048);                                 \
    bf16x8 A3 = *(const bf16x8*)(_gp + 3072);                                 \
    int4v _npk = *(const int4v*)(pcoal + (size_t)_pks * 64);                  \
    bf16x8 A0 = ast[cur][S][l];                                               \
    bf16x8 A1 = ast[cur][S][64 + l];                                          \
    unsigned _pkd = (unsigned)PKV[0] | ((unsigned)PKV[1] << 8)                \
                  | ((unsigned)PKV[2] << 16) | ((unsigned)PKV[3] << 24);      \
    unsigned _bp = (unsigned)__builtin_amdgcn_ds_bpermute(bpidx, (int)_pkd);  \
    bf16x8 b = deq(lut, _bp);

#define CSTEP_EVEN(S, PKV) {                                                  \
    CSTEP_BODY(S, PKV)                                                        \
    sb0 = __builtin_amdgcn_mfma_f32_16x16x32_bf16(A0, b, zro, 0, 0, 0);       \
    sb1 = __builtin_amdgcn_mfma_f32_16x16x32_bf16(A1, b, zro, 0, 0, 0);       \
    sb2 = __builtin_amdgcn_mfma_f32_16x16x32_bf16(A2, b, zro, 0, 0, 0);       \
    sb3 = __builtin_amdgcn_mfma_f32_16x16x32_bf16(A3, b, zro, 0, 0, 0);       \
    PKV = _npk; }

#define CSTEP_ODD(S, PKV, AM) {                                               \
    CSTEP_BODY(S, PKV)                                                        \
    sb0 = __builtin_amdgcn_mfma_f32_16x16x32_bf16(A0, b, sb0, 0, 0, 0);       \
    sb1 = __builtin_amdgcn_mfma_f32_16x16x32_bf16(A1, b, sb1, 0, 0, 0);       \
    sb2 = __builtin_amdgcn_mfma_f32_16x16x32_bf16(A2, b, sb2, 0, 0, 0);       \
    sb3 = __builtin_amdgcn_mfma_f32_16x16x32_bf16(A3, b, sb3, 0, 0, 0);       \
    mn0 += sb0 * (AM); mn1 += sb1 * (AM);                                     \
    mn2 += sb2 * (AM); mn3 += sb3 * (AM);                                     \
    PKV = _npk; }

// Fused NF4 dequant + GEMM (R12 skeleton + A-path pipe split + NC=16 TLP).
// pk: coalesced 16-sector loads + single packed ds_bpermute, 4-deep NAMED ring.
// A0/A1 via LDS staging (17KB total), A2/A3 direct from L2-resident xf.
// 4-kstep phases, counted vmcnt(12) so pk HBM loads stay in flight.
template<int NC>
__global__ __launch_bounds__(256, 4) void qlin_main(
    const int*   __restrict__ packed,
    const float* __restrict__ absmax,
    const unsigned short* __restrict__ xf,
    unsigned short* __restrict__ parts) {
  constexpr int KCn   = IN_K / NC;     // k per chunk
  constexpr int NIT   = KCn / 32;      // k-steps per chunk (16 for NC=16)
  constexpr int NITm1 = NIT - 1;
  constexpr int NPH   = NIT / 4;       // phases
  constexpr int AMX   = NIT / 2 - 1;   // last absmax group in chunk
  constexpr int LOG   = (NC == 16) ? 4 : 3;

  __shared__ SMem sm;
  auto& lutm = sm.s.lut;
  auto& ast  = sm.s.ast;
  {
    int t = threadIdx.x;
    unsigned lo = f2bf(NF4_TAB[t & 15]);
    unsigned hi = f2bf(NF4_TAB[(t >> 4) & 15]);
    lutm[t] = lo | (hi << 16);
  }
  __syncthreads();
  const unsigned int* lut = &lutm[0];

  const int l     = threadIdx.x & 63;
  const int w     = threadIdx.x >> 6;
  const int ntile = (int)blockIdx.x >> LOG;
  const int chunk = (int)blockIdx.x & (NC - 1);   // chunk%8 ~ XCD -> xf L2 locality
  const int colg0 = ntile * 64 + w * 16;
  const int col   = colg0 + (l & 15);
  const int kb    = l >> 4;
  const int kc0   = chunk * KCn;
  const int ksg0  = kc0 >> 5;

  // coalesced pk: lane l reads 16B piece (l&3) of col colg0+(l>>2); kstep stride 64B
  const char* pcoal = (const char*)packed
                    + ((size_t)(colg0 + (l >> 2)) * (IN_K / 2) + kc0 / 2) * 4
                    + (l & 3) * 16;
  // dest lane (c=l&15, q=l>>4) pulls from src lane 4c+q (byte index for bpermute)
  const int bpidx = (((l & 15) << 2) | (l >> 4)) << 2;

  const char* xfb = (const char*)xf + (size_t)ksg0 * 4096;   // chunk xf base
  const float* aptr = absmax + (size_t)col * 128 + (kc0 >> 6);

  const f32x4 zro = {0.f, 0.f, 0.f, 0.f};
  f32x4 mn0 = zro, mn1 = zro, mn2 = zro, mn3 = zro;
  f32x4 sb0, sb1, sb2, sb3;
  int4v pk0, pk1, pk2, pk3;

  // ---- prologue: absmax(2) -> stage phase0(2) -> [pin] -> pk ring(4)
  float amE = aptr[0], amO = aptr[1];
  STAGE(0, 0);
  __builtin_amdgcn_sched_barrier(0);
  pk0 = *(const int4v*)(pcoal);
  pk1 = *(const int4v*)(pcoal + 64);
  pk2 = *(const int4v*)(pcoal + 128);
  pk3 = *(const int4v*)(pcoal + 192);
  asm volatile("s_waitcnt vmcnt(4)" ::: "memory");   // stages+absmax retired
  __builtin_amdgcn_s_barrier();

  for (int ph = 0; ph < NPH; ++ph) {
    const int KS  = ph * 4;
    const int cur = ph & 1;

    int ia = 2 * ph + 2; if (ia > AMX) ia = AMX;
    int ib = 2 * ph + 3; if (ib > AMX) ib = AMX;
    float pmE = aptr[ia], pmO = aptr[ib];
    if (ph + 1 < NPH) STAGE(cur ^ 1, ph + 1);
    __builtin_amdgcn_sched_barrier(0);   // pin {absmax,stage} before kstep loads

    CSTEP_EVEN(0, pk0)
    CSTEP_ODD (1, pk1, amE)
    CSTEP_EVEN(2, pk2)
    CSTEP_ODD (3, pk3, amO)

    amE = pmE; amO = pmO;
    // vmcnt(12): allows the 4 ksteps' {A2,A3,pk} (12 youngest) outstanding;
    // stages+absmax (older) provably retired -> buf^1 ready for next phase.
    asm volatile("s_waitcnt vmcnt(12)" ::: "memory");
    asm volatile("s_waitcnt lgkmcnt(0)" ::: "memory"); // my reads of buf done
    __builtin_amdgcn_s_barrier();
  }

  // ---- epilogue: bf16-pack, transpose through the overlaid LDS tile, then
  // fully-contiguous tile-major stores. (All waves passed the final barrier
  // with lgkmcnt(0) -> ast/lut dead, tlb overlay safe.)
  {
    const int c  = w * 16 + (l & 15);        // block-local col
    const int r0 = kb * 4;
    sm.tlb[0  + r0 + 0][c] = f2bf(mn0[0]);
    sm.tlb[0  + r0 + 1][c] = f2bf(mn0[1]);
    sm.tlb[0  + r0 + 2][c] = f2bf(mn0[2]);
    sm.tlb[0  + r0 + 3][c] = f2bf(mn0[3]);
    sm.tlb[16 + r0 + 0][c] = f2bf(mn1[0]);
    sm.tlb[16 + r0 + 1][c] = f2bf(mn1[1]);
    sm.tlb[16 + r0 + 2][c] = f2bf(mn1[2]);
    sm.tlb[16 + r0 + 3][c] = f2bf(mn1[3]);
    sm.tlb[32 + r0 + 0][c] = f2bf(mn2[0]);
    sm.tlb[32 + r0 + 1][c] = f2bf(mn2[1]);
    sm.tlb[32 + r0 + 2][c] = f2bf(mn2[2]);
    sm.tlb[32 + r0 + 3][c] = f2bf(mn2[3]);
    sm.tlb[48 + r0 + 0][c] = f2bf(mn3[0]);
    sm.tlb[48 + r0 + 1][c] = f2bf(mn3[1]);
    sm.tlb[48 + r0 + 2][c] = f2bf(mn3[2]);
    sm.tlb[48 + r0 + 3][c] = f2bf(mn3[3]);
    __syncthreads();
    // parts layout: [chunk][tile][row 64][col 64] bf16 -> block tile contiguous
    unsigned short* po = parts + ((size_t)chunk * 128 + ntile) * 4096;
    const int t   = threadIdx.x;
    const int rr  = t >> 3;         // row within pass (0..31)
    const int oct = (t & 7) * 8;    // col octet
    #pragma unroll
    for (int p = 0; p < 2; ++p) {
      const int row = p * 32 + rr;
      bf16x8 v = *(const bf16x8*)&sm.tlb[row][oct];
      *(bf16x8*)(po + (size_t)row * 64 + oct) = v;
    }
  }
}

// reduce bf16 tile-major partials: out[row][tile*64+col] = sum_c parts + bias
template<int NC>
__global__ __launch_bounds__(256) void qlin_reduce(
    const unsigned short* __restrict__ parts,
    const float* __restrict__ bias,
    float*       __restrict__ out) {
  int e = blockIdx.x * 256 + threadIdx.x;          // octet index (8 cols)
  if (e >= M_ROWS * OUT_N / 8) return;
  const int tile = e >> 9;          // 512 octets per tile (64 rows x 8)
  const int rem  = e & 511;
  const int row  = rem >> 3;
  const int oct  = rem & 7;
  const size_t base = ((size_t)tile * 64 + row) * 64 + oct * 8;
  constexpr size_t CS = (size_t)128 * 64 * 64;     // chunk stride (elements)
  float s[8] = {0,0,0,0,0,0,0,0};
  #pragma unroll
  for (int c = 0; c < NC; ++c) {
    bf16x8 v = *(const bf16x8*)(parts + c * CS + base);
    #pragma unroll
    for (int j = 0; j < 8; ++j)
      s[j] += __uint_as_float(((unsigned)(unsigned short)v[j]) << 16);
  }
  const int colb = tile * 64 + oct * 8;
  const f32x4* bp = (const f32x4*)(bias + colb);
  f32x4 b0 = bp[0], b1 = bp[1];
  f32x4 o0, o1;
  o0[0] = s[0] + b0[0]; o0[1] = s[1] + b0[1];
  o0[2] = s[2] + b0[2]; o0[3] = s[3] + b0[3];
  o1[0] = s[4] + b1[0]; o1[1] = s[5] + b1[1];
  o1[2] = s[6] + b1[2]; o1[3] = s[7] + b1[3];
  float* op = out + (size_t)row * OUT_N + colb;
  *(f32x4*)op = o0;
  *(f32x4*)(op + 4) = o1;
}

extern "C" void kernel_launch(void* const* d_in, const int* in_sizes, int n_in,
                              void* d_out, int out_size, void* d_ws, size_t ws_size,
                              hipStream_t stream) {
  const float* x      = (const float*)d_in[0];
  const int*   packed = (const int*)d_in[1];
  const float* absmax = (const float*)d_in[2];
  const float* bias   = (const float*)d_in[3];
  float* out = (float*)d_out;

  unsigned short* xf    = (unsigned short*)d_ws;                      // 1 MB
  unsigned short* parts = (unsigned short*)((char*)d_ws + (1 << 20)); // NC MB bf16

  qlin_prep<<<(M_ROWS * IN_K / 8 + 255) / 256, 256, 0, stream>>>(x, xf);

  const size_t chunk_bytes = (size_t)128 * 64 * 64 * sizeof(unsigned short); // 1 MB
  const size_t need16 = (size_t)(1 << 20) + 16 * chunk_bytes;
  if (ws_size >= need16) {
    qlin_main<16><<<128 * 16, 256, 0, stream>>>(packed, absmax, xf, parts);
    qlin_reduce<16><<<(M_ROWS * OUT_N / 8 + 255) / 256, 256, 0, stream>>>(parts, bias, out);
  } else {
    qlin_main<8><<<128 * 8, 256, 0, stream>>>(packed, absmax, xf, parts);
    qlin_reduce<8><<<(M_ROWS * OUT_N / 8 + 255) / 256, 256, 0, stream>>>(parts, bias, out);
  }
}

// Round 16
// 38.790 us; speedup vs baseline: 1.1729x; 1.1034x over previous
//
#include <hip/hip_runtime.h>
#include <hip/hip_bf16.h>

#define OUT_N 8192
#define IN_K  8192
#define M_ROWS 64

typedef __attribute__((ext_vector_type(8))) short  bf16x8;
typedef __attribute__((ext_vector_type(4))) float  f32x4;
typedef __attribute__((ext_vector_type(4))) int    int4v;
typedef __attribute__((ext_vector_type(2))) int    int2v;

__device__ const float NF4_TAB[16] = {
  -1.0f, -0.6961928009986877f, -0.5250730514526367f, -0.39491748809814453f,
  -0.28444138169288635f, -0.18477343022823334f, -0.09105003625154495f, 0.0f,
  0.07958029955625534f, 0.16093020141124725f, 0.24611230850219726f,
  0.33791524171829224f, 0.44070982933044434f, 0.5626170039176941f,
  0.7229568362236023f, 1.0f };

static __device__ __forceinline__ unsigned short f2bf(float f) {
  union { __hip_bfloat16 h; unsigned short s; } u;
  u.h = __float2bfloat16(f);
  return u.s;
}

static __device__ __forceinline__ void gload_lds16(const void* g, void* s) {
  __builtin_amdgcn_global_load_lds((const __attribute__((address_space(1))) void*)g,
                                   (__attribute__((address_space(3))) void*)s,
                                   16, 0, 0);
}

// Repack x (fp32 [64][8192]) -> bf16 MFMA A-fragment order.
// xf[((ks*4 + mt)*64 + lane)*8 + j] = bf16(x[mt*16+(lane&15)][ks*32+(lane>>4)*8+j])
__global__ __launch_bounds__(256) void qlin_prep(const float* __restrict__ x,
                                                 unsigned short* __restrict__ xf) {
  int t = blockIdx.x * 256 + threadIdx.x;          // (ks, mt, lane)
  int lane = t & 63, mt = (t >> 6) & 3, ks = t >> 8;
  int ri = lane & 15, kbb = lane >> 4;
  const float* src = x + (size_t)(mt * 16 + ri) * IN_K + ks * 32 + kbb * 8;
  f32x4 a = *(const f32x4*)src;
  f32x4 c = *(const f32x4*)(src + 4);
  bf16x8 o;
  o[0] = (short)f2bf(a[0]); o[1] = (short)f2bf(a[1]);
  o[2] = (short)f2bf(a[2]); o[3] = (short)f2bf(a[3]);
  o[4] = (short)f2bf(c[0]); o[5] = (short)f2bf(c[1]);
  o[6] = (short)f2bf(c[2]); o[7] = (short)f2bf(c[3]);
  ((bf16x8*)xf)[t] = o;
}

// dequant a packed-4-codes dword: 4 pair-LUT reads -> 8 ready bf16 weights
static __device__ __forceinline__ bf16x8 deq(const unsigned int* lut, unsigned b) {
  int4v bw;
  bw[0] = (int)lut[b & 255];
  bw[1] = (int)lut[(b >> 8) & 255];
  bw[2] = (int)lut[(b >> 16) & 255];
  bw[3] = (int)lut[b >> 24];
  union { int4v i; bf16x8 h; } c; c.i = bw;
  return c.h;
}

// wave w stages k-step (4*PH + w) of the chunk into typed LDS buffer BUF, slot w.
#define STAGE(BUF, PH) {                                                      \
    const char* _s = xfb + (((size_t)(PH) * 4 + w) * 4096) + l * 16;          \
    gload_lds16(_s,        &ast[BUF][w][0]);                                  \
    gload_lds16(_s + 1024, &ast[BUF][w][64]);                                 \
    gload_lds16(_s + 2048, &ast[BUF][w][128]);                                \
    gload_lds16(_s + 3072, &ast[BUF][w][192]); }

// one k-step: typed ds_read A-frags, pack 4 code bytes -> ONE ds_bpermute,
// dequant, 4 MFMA, refill pk slot (+4 ahead, coalesced).
// EVEN opens a 64k group (C=0), ODD closes it (fold absmax into mn).
#define CSTEP_BODY(S, PKV)                                                    \
    int _nk = KS + (S) + 4; if (_nk > NITm1) _nk = NITm1;                     \
    int4v _npk = *(const int4v*)(pcoal + (size_t)_nk * 64);                   \
    bf16x8 A0 = ast[cur][S][l];                                               \
    bf16x8 A1 = ast[cur][S][64 + l];                                          \
    bf16x8 A2 = ast[cur][S][128 + l];                                         \
    bf16x8 A3 = ast[cur][S][192 + l];                                         \
    unsigned _pkd = (unsigned)PKV[0] | ((unsigned)PKV[1] << 8)                \
                  | ((unsigned)PKV[2] << 16) | ((unsigned)PKV[3] << 24);      \
    unsigned _bp = (unsigned)__builtin_amdgcn_ds_bpermute(bpidx, (int)_pkd);  \
    bf16x8 b = deq(lut, _bp);

#define CSTEP_EVEN(S, PKV) {                                                  \
    CSTEP_BODY(S, PKV)                                                        \
    sb0 = __builtin_amdgcn_mfma_f32_16x16x32_bf16(A0, b, zro, 0, 0, 0);       \
    sb1 = __builtin_amdgcn_mfma_f32_16x16x32_bf16(A1, b, zro, 0, 0, 0);       \
    sb2 = __builtin_amdgcn_mfma_f32_16x16x32_bf16(A2, b, zro, 0, 0, 0);       \
    sb3 = __builtin_amdgcn_mfma_f32_16x16x32_bf16(A3, b, zro, 0, 0, 0);       \
    PKV = _npk; }

#define CSTEP_ODD(S, PKV, AM) {                                               \
    CSTEP_BODY(S, PKV)                                                        \
    sb0 = __builtin_amdgcn_mfma_f32_16x16x32_bf16(A0, b, sb0, 0, 0, 0);       \
    sb1 = __builtin_amdgcn_mfma_f32_16x16x32_bf16(A1, b, sb1, 0, 0, 0);       \
    sb2 = __builtin_amdgcn_mfma_f32_16x16x32_bf16(A2, b, sb2, 0, 0, 0);       \
    sb3 = __builtin_amdgcn_mfma_f32_16x16x32_bf16(A3, b, sb3, 0, 0, 0);       \
    mn0 += sb0 * (AM); mn1 += sb1 * (AM);                                     \
    mn2 += sb2 * (AM); mn3 += sb3 * (AM);                                     \
    PKV = _npk; }

// Fused NF4 dequant + GEMM (proven 38.9 us configuration, restored verbatim).
// pk: coalesced 16-sector loads (16B/lane x 4 lanes = a col's exact 64B kstep
// slice; packed holds ONE code per int32, so this is traffic-exact) + SINGLE
// packed ds_bpermute, 4-deep NAMED ring (ring-4 fits the 64-VGPR budget).
// A: typed-LDS double-buffered staging (4 k-steps/phase), counted vmcnt(4).
template<int NC>
__global__ __launch_bounds__(256, 4) void qlin_main(
    const int*   __restrict__ packed,
    const float* __restrict__ absmax,
    const unsigned short* __restrict__ xf,
    unsigned short* __restrict__ parts) {
  constexpr int KCn   = IN_K / NC;     // k per chunk
  constexpr int NIT   = KCn / 32;      // k-steps per chunk (32 for NC=8)
  constexpr int NITm1 = NIT - 1;
  constexpr int NPH   = NIT / 4;       // phases
  constexpr int AMX   = NIT / 2 - 1;   // last absmax group in chunk
  constexpr int LOG   = (NC == 8) ? 3 : 2;

  __shared__ unsigned int lut[256];    // byte -> {bf16(nf4[lo]), bf16(nf4[hi])}
  __shared__ bf16x8 ast[2][4][256];    // typed: [buf][kstep-in-phase][mt*64+lane]
  {
    int t = threadIdx.x;
    unsigned lo = f2bf(NF4_TAB[t & 15]);
    unsigned hi = f2bf(NF4_TAB[(t >> 4) & 15]);
    lut[t] = lo | (hi << 16);
  }
  __syncthreads();

  const int l     = threadIdx.x & 63;
  const int w     = threadIdx.x >> 6;
  const int ntile = (int)blockIdx.x >> LOG;
  const int chunk = (int)blockIdx.x & (NC - 1);   // ~XCD id -> xf L2 locality
  const int colg0 = ntile * 64 + w * 16;
  const int col   = colg0 + (l & 15);
  const int kb    = l >> 4;
  const int kc0   = chunk * KCn;
  const int ksg0  = kc0 >> 5;

  // coalesced pk: lane l reads 16B piece (l&3) of col colg0+(l>>2); kstep stride 64B
  const char* pcoal = (const char*)packed
                    + ((size_t)(colg0 + (l >> 2)) * (IN_K / 2) + kc0 / 2) * 4
                    + (l & 3) * 16;
  // dest lane (c=l&15, q=l>>4) pulls from src lane 4c+q (byte index for bpermute)
  const int bpidx = (((l & 15) << 2) | (l >> 4)) << 2;

  const char* xfb = (const char*)xf + (size_t)ksg0 * 4096;   // chunk xf base
  const float* aptr = absmax + (size_t)col * 128 + (kc0 >> 6);

  const f32x4 zro = {0.f, 0.f, 0.f, 0.f};
  f32x4 mn0 = zro, mn1 = zro, mn2 = zro, mn3 = zro;
  f32x4 sb0, sb1, sb2, sb3;
  int4v pk0, pk1, pk2, pk3;

  // ---- prologue: absmax(2) -> stage phase0(4) -> [pin] -> pk ring(4)
  float amE = aptr[0], amO = aptr[1];
  STAGE(0, 0);
  __builtin_amdgcn_sched_barrier(0);
  pk0 = *(const int4v*)(pcoal);
  pk1 = *(const int4v*)(pcoal + 64);
  pk2 = *(const int4v*)(pcoal + 128);
  pk3 = *(const int4v*)(pcoal + 192);
  asm volatile("s_waitcnt vmcnt(4)" ::: "memory");   // stages+absmax retired
  __builtin_amdgcn_s_barrier();

  for (int ph = 0; ph < NPH; ++ph) {
    const int KS  = ph * 4;
    const int cur = ph & 1;

    int ia = 2 * ph + 2; if (ia > AMX) ia = AMX;
    int ib = 2 * ph + 3; if (ib > AMX) ib = AMX;
    float pmE = aptr[ia], pmO = aptr[ib];
    if (ph + 1 < NPH) STAGE(cur ^ 1, ph + 1);
    __builtin_amdgcn_sched_barrier(0);   // pin {absmax,stage} before {pk}

    CSTEP_EVEN(0, pk0)
    CSTEP_ODD (1, pk1, amE)
    CSTEP_EVEN(2, pk2)
    CSTEP_ODD (3, pk3, amO)

    amE = pmE; amO = pmO;
    // vmcnt(4): the 4 pk loads (youngest) may stay in flight; absmax+stages
    // (older, pinned) are provably retired -> buf^1 is ready for next phase.
    asm volatile("s_waitcnt vmcnt(4)" ::: "memory");
    asm volatile("s_waitcnt lgkmcnt(0)" ::: "memory"); // my reads of buf done
    __builtin_amdgcn_s_barrier();
  }

  // ---- epilogue: transpose 64x64 fp32 tile through LDS (reuse ast, stride 68
  // dwords to spread banks), then bf16-pack + fully-contiguous tile-major stores.
  {
    float* tl = (float*)&ast[0][0][0];       // 64*68*4 = 17408 B <= 32 KB
    const int c  = w * 16 + (l & 15);        // block-local col
    const int r0 = kb * 4;
    tl[(0  + r0 + 0) * 68 + c] = mn0[0];
    tl[(0  + r0 + 1) * 68 + c] = mn0[1];
    tl[(0  + r0 + 2) * 68 + c] = mn0[2];
    tl[(0  + r0 + 3) * 68 + c] = mn0[3];
    tl[(16 + r0 + 0) * 68 + c] = mn1[0];
    tl[(16 + r0 + 1) * 68 + c] = mn1[1];
    tl[(16 + r0 + 2) * 68 + c] = mn1[2];
    tl[(16 + r0 + 3) * 68 + c] = mn1[3];
    tl[(32 + r0 + 0) * 68 + c] = mn2[0];
    tl[(32 + r0 + 1) * 68 + c] = mn2[1];
    tl[(32 + r0 + 2) * 68 + c] = mn2[2];
    tl[(32 + r0 + 3) * 68 + c] = mn2[3];
    tl[(48 + r0 + 0) * 68 + c] = mn3[0];
    tl[(48 + r0 + 1) * 68 + c] = mn3[1];
    tl[(48 + r0 + 2) * 68 + c] = mn3[2];
    tl[(48 + r0 + 3) * 68 + c] = mn3[3];
    __syncthreads();
    // parts layout: [chunk][tile][row 64][col 64] bf16 -> block tile contiguous
    unsigned short* po = parts + ((size_t)chunk * 128 + ntile) * 4096;
    const int t  = threadIdx.x;
    const int rr = t >> 4;          // row within pass (0..15)
    const int cq = (t & 15) * 4;    // col quad
    #pragma unroll
    for (int p = 0; p < 4; ++p) {
      const int row = p * 16 + rr;
      f32x4 v = *(const f32x4*)&tl[row * 68 + cq];
      int2v o;
      o[0] = (int)(f2bf(v[0]) | ((unsigned)f2bf(v[1]) << 16));
      o[1] = (int)(f2bf(v[2]) | ((unsigned)f2bf(v[3]) << 16));
      *(int2v*)(po + (size_t)row * 64 + cq) = o;
    }
  }
}

// reduce bf16 tile-major partials: out[row][tile*64+col] = sum_c parts + bias
template<int NC>
__global__ __launch_bounds__(256) void qlin_reduce(
    const unsigned short* __restrict__ parts,
    const float* __restrict__ bias,
    float*       __restrict__ out) {
  int e = blockIdx.x * 256 + threadIdx.x;          // octet index (8 cols)
  if (e >= M_ROWS * OUT_N / 8) return;
  const int tile = e >> 9;          // 512 octets per tile (64 rows x 8)
  const int rem  = e & 511;
  const int row  = rem >> 3;
  const int oct  = rem & 7;
  const size_t base = ((size_t)tile * 64 + row) * 64 + oct * 8;
  constexpr size_t CS = (size_t)128 * 64 * 64;     // chunk stride (elements)
  float s[8] = {0,0,0,0,0,0,0,0};
  #pragma unroll
  for (int c = 0; c < NC; ++c) {
    bf16x8 v = *(const bf16x8*)(parts + c * CS + base);
    #pragma unroll
    for (int j = 0; j < 8; ++j)
      s[j] += __uint_as_float(((unsigned)(unsigned short)v[j]) << 16);
  }
  const int colb = tile * 64 + oct * 8;
  const f32x4* bp = (const f32x4*)(bias + colb);
  f32x4 b0 = bp[0], b1 = bp[1];
  f32x4 o0, o1;
  o0[0] = s[0] + b0[0]; o0[1] = s[1] + b0[1];
  o0[2] = s[2] + b0[2]; o0[3] = s[3] + b0[3];
  o1[0] = s[4] + b1[0]; o1[1] = s[5] + b1[1];
  o1[2] = s[6] + b1[2]; o1[3] = s[7] + b1[3];
  float* op = out + (size_t)row * OUT_N + colb;
  *(f32x4*)op = o0;
  *(f32x4*)(op + 4) = o1;
}

extern "C" void kernel_launch(void* const* d_in, const int* in_sizes, int n_in,
                              void* d_out, int out_size, void* d_ws, size_t ws_size,
                              hipStream_t stream) {
  const float* x      = (const float*)d_in[0];
  const int*   packed = (const int*)d_in[1];
  const float* absmax = (const float*)d_in[2];
  const float* bias   = (const float*)d_in[3];
  float* out = (float*)d_out;

  unsigned short* xf    = (unsigned short*)d_ws;                      // 1 MB
  unsigned short* parts = (unsigned short*)((char*)d_ws + (1 << 20)); // NC MB bf16

  qlin_prep<<<(M_ROWS * IN_K / 8 + 255) / 256, 256, 0, stream>>>(x, xf);

  const size_t chunk_bytes = (size_t)128 * 64 * 64 * sizeof(unsigned short); // 1 MB
  const size_t need8 = (size_t)(1 << 20) + 8 * chunk_bytes;
  if (ws_size >= need8) {
    qlin_main<8><<<128 * 8, 256, 0, stream>>>(packed, absmax, xf, parts);
    qlin_reduce<8><<<(M_ROWS * OUT_N / 8 + 255) / 256, 256, 0, stream>>>(parts, bias, out);
  } else {
    qlin_main<4><<<128 * 4, 256, 0, stream>>>(packed, absmax, xf, parts);
    qlin_reduce<4><<<(M_ROWS * OUT_N / 8 + 255) / 256, 256, 0, stream>>>(parts, bias, out);
  }
}